// Round 11
// baseline (234.740 us; speedup 1.0000x reference)
//
#include <hip/hip_runtime.h>

typedef unsigned short u16;
typedef unsigned int u32;

#define SPA 2744        // 14*14*14 tokens
#define CH  768
#define NH  12
#define DH  64
#define BB  2
#define TC  2304        // 3*CH
#define MTOT (BB*SPA)   // 5488
#define LNB 343         // LN blocks (16 tokens each, 343*16 = 5488 exactly)
#define CVTB 2304       // weight-cvt blocks, dispatched after LN

typedef __bf16 bf16x8_t __attribute__((ext_vector_type(8)));
typedef __bf16 bf16x4_t __attribute__((ext_vector_type(4)));
typedef short  s16x4    __attribute__((ext_vector_type(4)));
typedef float  f32x4_t  __attribute__((ext_vector_type(4)));

static __device__ __forceinline__ u16 f2bf(float f) {
    union { float f; u32 u; } v; v.f = f;
    u32 u = v.u;
    u += 0x7fffu + ((u >> 16) & 1u);   // RNE
    return (u16)(u >> 16);
}

// async global->LDS, 16B per lane. LDS dest = wave-uniform base + lane*16.
static __device__ __forceinline__ void gld16(const u16* g, u16* l) {
    __builtin_amdgcn_global_load_lds(
        (const __attribute__((address_space(1))) u32*)(size_t)g,
        (__attribute__((address_space(3))) u32*)(u32)(size_t)l, 16, 0, 0);
}

// ---------------- fused: LayerNorm (blocks < LNB, FIRST) + weight cvt ----------
__global__ __launch_bounds__(256) void cvtln_kernel(const float* __restrict__ qkv_w,
                                                    u16* __restrict__ qkvw_bf, int n4a,
                                                    const float* __restrict__ out_w,
                                                    u16* __restrict__ outw_bf,
                                                    const float* __restrict__ x,
                                                    const float* __restrict__ w,
                                                    const float* __restrict__ bta,
                                                    u16* __restrict__ tn) {
    int tid = threadIdx.x;
    if (blockIdx.x >= LNB) {
        int i = (blockIdx.x - LNB) * 256 + tid;   // covers n4a + n4b exactly
        const float* src; u16* dst; int idx;
        if (i < n4a) { src = qkv_w; dst = qkvw_bf; idx = i; }
        else { src = out_w; dst = outw_bf; idx = i - n4a; }
        float4 f = ((const float4*)src)[idx];
        uint2 o;
        o.x = (u32)f2bf(f.x) | ((u32)f2bf(f.y) << 16);
        o.y = (u32)f2bf(f.z) | ((u32)f2bf(f.w) << 16);
        ((uint2*)dst)[idx] = o;
        return;
    }
    int bid = blockIdx.x;                         // [0,343)
    __shared__ f32x4_t redS[4][4];
    __shared__ f32x4_t redQ[4][4];
    __shared__ u16 T[64][22];                     // [ch_local][token], pad 22
    int grp = tid & 3, chl = tid >> 2;            // grp: 4 token-groups, chl in [0,64)
    int wvi = tid >> 6, lane = tid & 63;
    int tok0 = bid * 16 + grp * 4;                // groups of 4 never straddle b
    int b = tok0 / SPA, n = tok0 - b * SPA;
    const float* base = x + (size_t)b * CH * SPA + n;

    f32x4_t s4 = {0.f, 0.f, 0.f, 0.f}, q4 = {0.f, 0.f, 0.f, 0.f};
    for (int c0 = 0; c0 < CH; c0 += 64) {
        float4 v = *(const float4*)(base + (size_t)(c0 + chl) * SPA);
        s4[0] += v.x; s4[1] += v.y; s4[2] += v.z; s4[3] += v.w;
        q4[0] += v.x * v.x; q4[1] += v.y * v.y; q4[2] += v.z * v.z; q4[3] += v.w * v.w;
    }
#pragma unroll
    for (int m = 4; m <= 32; m <<= 1)
#pragma unroll
        for (int e = 0; e < 4; e++) {
            s4[e] += __shfl_xor(s4[e], m);
            q4[e] += __shfl_xor(q4[e], m);
        }
    if (lane < 4) { redS[wvi][lane] = s4; redQ[wvi][lane] = q4; }
    __syncthreads();
    f32x4_t st = redS[0][grp], qt = redQ[0][grp];
#pragma unroll
    for (int wv2 = 1; wv2 < 4; wv2++) {
        f32x4_t a = redS[wv2][grp], c = redQ[wv2][grp];
#pragma unroll
        for (int e = 0; e < 4; e++) { st[e] += a[e]; qt[e] += c[e]; }
    }
    f32x4_t mean4, rstd4;
#pragma unroll
    for (int e = 0; e < 4; e++) {
        mean4[e] = st[e] * (1.0f / CH);
        rstd4[e] = rsqrtf(qt[e] * (1.0f / CH) - mean4[e] * mean4[e] + 1e-5f);
    }

    int tokl = tid >> 4, qq = tid & 15;           // tokl in [0,16), qq in [0,16)
    int g2 = bid * 16 + tokl;                     // always < MTOT (343*16 = 5488)
    for (int c0 = 0; c0 < CH; c0 += 64) {
        __syncthreads();
        {
            int cc = c0 + chl;
            float4 v = *(const float4*)(base + (size_t)cc * SPA);
            float ws = w[cc], bs = bta[cc];
            union { u16 h4[4]; uint2 u; } pk;
            pk.h4[0] = f2bf((v.x - mean4[0]) * rstd4[0] * ws + bs);
            pk.h4[1] = f2bf((v.y - mean4[1]) * rstd4[1] * ws + bs);
            pk.h4[2] = f2bf((v.z - mean4[2]) * rstd4[2] * ws + bs);
            pk.h4[3] = f2bf((v.w - mean4[3]) * rstd4[3] * ws + bs);
            *(uint2*)(&T[chl][grp * 4]) = pk.u;
        }
        __syncthreads();
        union { u16 h[4]; uint2 u; } pk;
#pragma unroll
        for (int e = 0; e < 4; e++) pk.h[e] = T[qq * 4 + e][tokl];
        *(uint2*)(tn + (size_t)g2 * CH + c0 + qq * 4) = pk.u;
    }
}

// ---------------- QKV GEMM: C[m][n] = tn[m][k]*W[n][k] ----------------
// Q/K: scatter epilogue to [bh][n][d]. V (which==2): wave-local LDS transpose
// epilogue writes vt[bh][d][n] directly -- vtrans kernel eliminated. Each
// wave's 64tok x 64rem tile is wave-private, so the transpose needs NO
// barriers (per-wave Tv buffer; ds_write -> ds_read same-wave ordering is
// handled by compiler waitcnts). Bank aliasing 2-way on both phases (free).
__global__ __launch_bounds__(256, 3) void gemm_qkv(const u16* __restrict__ A,
                                                   const u16* __restrict__ Bw,
                                                   u16* __restrict__ out0,
                                                   u16* __restrict__ out1,
                                                   u16* __restrict__ vtb) {
    const int M = MTOT, K = CH;
    __shared__ __align__(16) u16 As[128 * 32];
    __shared__ __align__(16) u16 Bs[128 * 32];
    __shared__ __align__(16) u16 Tv[4][64 * 72];   // per-wave V transpose staging
    int tid = threadIdx.x;
    int m0 = blockIdx.y * 128;
    int n0 = blockIdx.x * 128;
    int wv = tid >> 6, lane = tid & 63;
    int wm = (wv >> 1) * 64, wn = (wv & 1) * 64;
    int quad = lane >> 4, l16 = lane & 15;

    f32x4_t zero = {0.f, 0.f, 0.f, 0.f};
    f32x4_t acc[4][4];
#pragma unroll
    for (int i = 0; i < 4; i++)
#pragma unroll
        for (int j = 0; j < 4; j++) acc[i][j] = zero;

    int rl = lane >> 2, pos = lane & 3;
    int sw = (l16 >> 1) & 3;
    for (int k0 = 0; k0 < K; k0 += 32) {
        __syncthreads();
#pragma unroll
        for (int p = 0; p < 2; p++) {
            int rbase = p * 64 + wv * 16;
            int row = rbase + rl;
            int gch = pos ^ ((row >> 1) & 3);
            int gm = m0 + row; if (gm >= M) gm = M - 1;
            gld16(A + (size_t)gm * K + k0 + gch * 8, As + rbase * 32);
            gld16(Bw + (size_t)(n0 + row) * K + k0 + gch * 8, Bs + rbase * 32);
        }
        __syncthreads();
        bf16x8_t af[4], bfr[4];
#pragma unroll
        for (int i = 0; i < 4; i++)
            af[i] = *(const bf16x8_t*)(As + (wm + i * 16 + l16) * 32 + ((quad ^ sw) * 8));
#pragma unroll
        for (int j = 0; j < 4; j++)
            bfr[j] = *(const bf16x8_t*)(Bs + (wn + j * 16 + l16) * 32 + ((quad ^ sw) * 8));
#pragma unroll
        for (int i = 0; i < 4; i++)
#pragma unroll
            for (int j = 0; j < 4; j++)
                acc[i][j] = __builtin_amdgcn_mfma_f32_16x16x32_bf16(af[i], bfr[j], acc[i][j], 0, 0, 0);
    }

    int which = n0 / CH;                  // block-uniform (CH % 128 == 0)
    int rb = n0 - which * CH;

    if (which == 2) {
        // ---- V: wave-local transpose, store vt[bh][d][n] directly ----
        u16* Twv = &Tv[wv][0];
#pragma unroll
        for (int i = 0; i < 4; i++)
#pragma unroll
            for (int j = 0; j < 4; j++) {
                union { u16 h4[4]; uint2 u; } pk;
#pragma unroll
                for (int r = 0; r < 4; r++) pk.h4[r] = f2bf(acc[i][j][r]);
                *(uint2*)(&Twv[(j * 16 + l16) * 72 + i * 16 + quad * 4]) = pk.u;
            }
        // same-wave read-back (no barrier needed)
        int rd = lane >> 3, tc8 = (lane & 7) * 8;
#pragma unroll
        for (int rr = 0; rr < 8; rr++) {
            int row = rr * 8 + rd;              // rem_local
            int rem = rb + wn + row;
            int hh = rem >> 6, dd = rem & 63;
            int t0 = m0 + wm + tc8;             // token chunk (8-aligned, SPA%8==0)
            if (t0 < MTOT) {
                int b2 = t0 / SPA, n2 = t0 - b2 * SPA;
                *(int4*)(vtb + ((size_t)(b2 * NH + hh) * DH + dd) * SPA + n2) =
                    *(const int4*)(&Twv[row * 72 + tc8]);
            }
        }
        return;
    }

    u16* base = (which == 0) ? out0 : out1;
    float qs = (which == 0) ? 0.18033688011112042f : 1.0f;  // dh^-0.5*log2(e)
#pragma unroll
    for (int i = 0; i < 4; i++)
#pragma unroll
        for (int r = 0; r < 4; r++) {
            int gm = m0 + wm + i * 16 + quad * 4 + r;
            if (gm < M) {
                int b = gm / SPA, n = gm - b * SPA;
#pragma unroll
                for (int j = 0; j < 4; j++) {
                    int rem = rb + wn + j * 16 + l16;
                    int h = rem >> 6, d = rem & 63;
                    base[((size_t)(b * NH + h) * SPA + n) * DH + d] = f2bf(acc[i][j][r] * qs);
                }
            }
        }
}

// ---------------- out-proj GEMM, 128x64 tiles, fused bias+residual epilogue ----
__global__ __launch_bounds__(256, 4) void gemm_out(const u16* __restrict__ A,
                                                   const u16* __restrict__ Bw,
                                                   const float* __restrict__ xres,
                                                   const float* __restrict__ ob,
                                                   float* __restrict__ fout) {
    const int M = MTOT, K = CH;
    __shared__ __align__(16) u16 As[128 * 32];
    __shared__ __align__(16) u16 Bs[64 * 32];
    int tid = threadIdx.x;
    int m0 = blockIdx.y * 128;
    int n0 = blockIdx.x * 64;
    int wv = tid >> 6, lane = tid & 63;
    int wm = (wv >> 1) * 64, wn = (wv & 1) * 32;
    int quad = lane >> 4, l16 = lane & 15;

    f32x4_t zero = {0.f, 0.f, 0.f, 0.f};
    f32x4_t acc[4][2];
#pragma unroll
    for (int i = 0; i < 4; i++)
#pragma unroll
        for (int j = 0; j < 2; j++) acc[i][j] = zero;

    int rl = lane >> 2, pos = lane & 3;
    int sw = (l16 >> 1) & 3;
    for (int k0 = 0; k0 < K; k0 += 32) {
        __syncthreads();
#pragma unroll
        for (int p = 0; p < 2; p++) {
            int rbase = p * 64 + wv * 16;
            int row = rbase + rl;
            int gch = pos ^ ((row >> 1) & 3);
            int gm = m0 + row; if (gm >= M) gm = M - 1;
            gld16(A + (size_t)gm * K + k0 + gch * 8, As + rbase * 32);
        }
        {
            int row = wv * 16 + rl;
            int gch = pos ^ ((row >> 1) & 3);
            gld16(Bw + (size_t)(n0 + row) * K + k0 + gch * 8, Bs + (wv * 16) * 32);
        }
        __syncthreads();
        bf16x8_t af[4], bfr[2];
#pragma unroll
        for (int i = 0; i < 4; i++)
            af[i] = *(const bf16x8_t*)(As + (wm + i * 16 + l16) * 32 + ((quad ^ sw) * 8));
#pragma unroll
        for (int j = 0; j < 2; j++)
            bfr[j] = *(const bf16x8_t*)(Bs + (wn + j * 16 + l16) * 32 + ((quad ^ sw) * 8));
#pragma unroll
        for (int i = 0; i < 4; i++)
#pragma unroll
            for (int j = 0; j < 2; j++)
                acc[i][j] = __builtin_amdgcn_mfma_f32_16x16x32_bf16(af[i], bfr[j], acc[i][j], 0, 0, 0);
    }

    // fused: lane holds 4 consecutive tokens (quad*4+r) for channel gn
#pragma unroll
    for (int i = 0; i < 4; i++) {
        int gm0 = m0 + wm + i * 16 + quad * 4;
        if (gm0 < M) {                    // groups of 4, M%4==0, SPA%4==0
            int b = gm0 / SPA;
            int n = gm0 - b * SPA;
#pragma unroll
            for (int j = 0; j < 2; j++) {
                int gn = n0 + wn + j * 16 + l16;
                size_t xo = ((size_t)(b * CH + gn)) * SPA + n;
                float4 xv = *(const float4*)(xres + xo);
                float bias = ob[gn];
                float4 rr;
                rr.x = xv.x + bias + acc[i][j][0];
                rr.y = xv.y + bias + acc[i][j][1];
                rr.z = xv.z + bias + acc[i][j][2];
                rr.w = xv.w + bias + acc[i][j][3];
                *(float4*)(fout + xo) = rr;
            }
        }
    }
}

// ---------------- flash attention v17: q64 tiles, wave-level kv-split ----------------
// (unchanged from round 8 best: ~94 us attn, occupancy ~21)
__global__ __launch_bounds__(256, 3) void attn_kernel(const u16* __restrict__ q,
                                                      const u16* __restrict__ k,
                                                      const u16* __restrict__ vt,
                                                      u16* __restrict__ out) {
    __shared__ __align__(16) u16 Kbuf[2][96 * 64];    // [kv_local][d] swizzled
    __shared__ __align__(16) u16 Vbuf[2][64 * 108];   // [d][kv_local] padded
    int g = blockIdx.x;                 // 1032 = 8 xcd * (3 bh * 43 qtiles)
    int xcd = g & 7, slot = g >> 3;     // slot in [0,129)
    int bh = xcd * 3 + slot % 3;
    int qg = slot / 3;                  // [0,43)
    int b = bh / NH, h = bh - b * NH;
    int tid = threadIdx.x;
    int wv = tid >> 6, lane = tid & 63;
    int quad = lane >> 4, l16 = lane & 15;
    int qhalf = wv & 1, khalf = wv >> 1;
    int koff = khalf * 48;              // this wave's kv-local window base
    int q0w = qg * 64 + qhalf * 32;

    const u16* qgp = q + (size_t)bh * SPA * DH;
    const u16* kg = k + (size_t)bh * SPA * DH;
    const u16* vg = vt + (size_t)bh * DH * SPA;

    bf16x8_t bq[2][2];
    int qglob[2];
#pragma unroll
    for (int qf = 0; qf < 2; qf++) {
        int qq = q0w + qf * 16 + l16;
        qglob[qf] = qq;
        int qld = (qq < SPA) ? qq : (SPA - 1);
#pragma unroll
        for (int ks = 0; ks < 2; ks++)
            bq[qf][ks] = *(const bf16x8_t*)(qgp + (size_t)qld * DH + ks * 32 + quad * 8);
    }

    f32x4_t zero = {0.f, 0.f, 0.f, 0.f};
    f32x4_t o[2][4];
#pragma unroll
    for (int qf = 0; qf < 2; qf++)
#pragma unroll
        for (int i = 0; i < 4; i++) o[qf][i] = zero;
    f32x4_t lacc[2];
    lacc[0] = zero; lacc[1] = zero;
    s16x4 ones;
    ones[0] = ones[1] = ones[2] = ones[3] = (short)0x3F80;  // bf16 1.0 x4

    int rl8 = lane >> 3, pos8 = lane & 7;
    int sw8 = l16 & 7;
    int vd = tid >> 2, vc = (tid & 3) * 24;   // 24 kv per thread (96/4)

    // ---- prologue: stage super-tile 0 (96 kv, all waves) ----
#pragma unroll
    for (int p = 0; p < 3; p++) {
        int rbase = p * 32 + wv * 8;
        int row = rbase + rl8;
        int gch = pos8 ^ (row & 7);
        gld16(kg + (size_t)row * DH + gch * 8, Kbuf[0] + rbase * 64);
    }
#pragma unroll
    for (int s2 = 0; s2 < 3; s2++)
        *(int4*)(Vbuf[0] + vd * 108 + vc + s2 * 8) =
            *(const int4*)(vg + (size_t)vd * SPA + vc + s2 * 8);

    for (int si = 0; si < 29; si++) {           // 29*96 = 2784 >= 2744
        __syncthreads();
        int cur = si & 1, nxt = cur ^ 1;
        int kv0 = si * 96;
        bool hn = (si < 28);
        int4 vp0, vp1, vp2;
        if (hn) {
            int kb = kv0 + 96;
#pragma unroll
            for (int p = 0; p < 3; p++) {
                int rbase = p * 32 + wv * 8;
                int row = rbase + rl8;
                int gch = pos8 ^ (row & 7);
                int kr = kb + row; if (kr >= SPA) kr = SPA - 1;
                gld16(kg + (size_t)kr * DH + gch * 8, Kbuf[nxt] + rbase * 64);
            }
            int c0 = kb + vc;
            int a0 = c0;      if (a0 > SPA - 8) a0 = SPA - 8;
            int a1 = c0 + 8;  if (a1 > SPA - 8) a1 = SPA - 8;
            int a2 = c0 + 16; if (a2 > SPA - 8) a2 = SPA - 8;
            vp0 = *(const int4*)(vg + (size_t)vd * SPA + a0);
            vp1 = *(const int4*)(vg + (size_t)vd * SPA + a1);
            vp2 = *(const int4*)(vg + (size_t)vd * SPA + a2);
        }

        // ---- QK + exp over this wave's 48-kv window ----
        s16x4 bp[2][3];
#pragma unroll
        for (int i = 0; i < 3; i++) {
            const u16* krow = Kbuf[cur] + (koff + i * 16 + l16) * 64;
            bf16x8_t ak0 = *(const bf16x8_t*)(krow + ((quad ^ sw8) * 8));
            bf16x8_t ak1 = *(const bf16x8_t*)(krow + (((4 + quad) ^ sw8) * 8));
            f32x4_t s0 = __builtin_amdgcn_mfma_f32_16x16x32_bf16(ak0, bq[0][0], zero, 0, 0, 0);
            s0 = __builtin_amdgcn_mfma_f32_16x16x32_bf16(ak1, bq[0][1], s0, 0, 0, 0);
            f32x4_t s1 = __builtin_amdgcn_mfma_f32_16x16x32_bf16(ak0, bq[1][0], zero, 0, 0, 0);
            s1 = __builtin_amdgcn_mfma_f32_16x16x32_bf16(ak1, bq[1][1], s1, 0, 0, 0);
            bf16x4_t p0, p1;
            if (si != 28) {
#pragma unroll
                for (int r = 0; r < 4; r++) {
                    p0[r] = (__bf16)__builtin_amdgcn_exp2f(s0[r]);
                    p1[r] = (__bf16)__builtin_amdgcn_exp2f(s1[r]);
                }
            } else {
#pragma unroll
                for (int r = 0; r < 4; r++) {
                    float e0 = __builtin_amdgcn_exp2f(s0[r]);
                    float e1 = __builtin_amdgcn_exp2f(s1[r]);
                    bool bad = (kv0 + koff + i * 16 + quad * 4 + r) >= SPA;
                    p0[r] = (__bf16)(bad ? 0.f : e0);
                    p1[r] = (__bf16)(bad ? 0.f : e1);
                }
            }
            union { bf16x4_t b; s16x4 s; } u0, u1;
            u0.b = p0; u1.b = p1;
            bp[0][i] = u0.s; bp[1][i] = u1.s;
        }

        // park next V tile (loads are QK-phase old by now)
        if (hn) {
            *(int4*)(Vbuf[nxt] + vd * 108 + vc)      = vp0;
            *(int4*)(Vbuf[nxt] + vd * 108 + vc + 8)  = vp1;
            *(int4*)(Vbuf[nxt] + vd * 108 + vc + 16) = vp2;
        }

        // ---- l += ones·P ; O^T += V^T·P (this wave's kv window) ----
#pragma unroll
        for (int c = 0; c < 3; c++) {
            lacc[0] = __builtin_amdgcn_mfma_f32_16x16x16bf16_1k(ones, bp[0][c], lacc[0], 0, 0, 0);
            lacc[1] = __builtin_amdgcn_mfma_f32_16x16x16bf16_1k(ones, bp[1][c], lacc[1], 0, 0, 0);
#pragma unroll
            for (int i = 0; i < 4; i++) {
                s16x4 av = *(const s16x4*)(Vbuf[cur] + (i * 16 + l16) * 108 + koff + c * 16 + quad * 4);
                o[0][i] = __builtin_amdgcn_mfma_f32_16x16x16bf16_1k(av, bp[0][c], o[0][i], 0, 0, 0);
                o[1][i] = __builtin_amdgcn_mfma_f32_16x16x16bf16_1k(av, bp[1][c], o[1][i], 0, 0, 0);
            }
        }
    }

    // ---- combine kv-halves through LDS (reuse Kbuf; 128 lanes x 36 f32) ----
    __syncthreads();
    float* lsh = (float*)Kbuf;
    if (wv >= 2) {
        int base = ((wv - 2) * 64 + lane) * 36;
#pragma unroll
        for (int qf = 0; qf < 2; qf++)
#pragma unroll
            for (int i = 0; i < 4; i++)
                *(f32x4_t*)(lsh + base + qf * 16 + i * 4) = o[qf][i];
        lsh[base + 32] = lacc[0][0];
        lsh[base + 33] = lacc[1][0];
    }
    __syncthreads();
    if (wv < 2) {
        int base = (wv * 64 + lane) * 36;
#pragma unroll
        for (int qf = 0; qf < 2; qf++)
#pragma unroll
            for (int i = 0; i < 4; i++) {
                f32x4_t t = *(const f32x4_t*)(lsh + base + qf * 16 + i * 4);
#pragma unroll
                for (int r = 0; r < 4; r++) o[qf][i][r] += t[r];
            }
        float lsum[2];
        lsum[0] = lacc[0][0] + lsh[base + 32];
        lsum[1] = lacc[1][0] + lsh[base + 33];
#pragma unroll
        for (int qf = 0; qf < 2; qf++) {
            int qq = qglob[qf];
            if (qq < SPA) {
                float inv = 1.0f / lsum[qf];
                u16* op = out + ((size_t)(b * SPA + qq)) * CH + h * DH;
#pragma unroll
                for (int i = 0; i < 4; i++) {
                    bf16x4_t ov;
#pragma unroll
                    for (int r = 0; r < 4; r++) ov[r] = (__bf16)(o[qf][i][r] * inv);
                    *(bf16x4_t*)(op + i * 16 + quad * 4) = ov;
                }
            }
        }
    }
}

extern "C" void kernel_launch(void* const* d_in, const int* in_sizes, int n_in,
                              void* d_out, int out_size, void* d_ws, size_t ws_size,
                              hipStream_t stream) {
    const float* x      = (const float*)d_in[0];
    const float* norm_w = (const float*)d_in[1];
    const float* norm_b = (const float*)d_in[2];
    const float* qkv_w  = (const float*)d_in[3];
    const float* out_w  = (const float*)d_in[4];
    const float* out_b  = (const float*)d_in[5];
    float* out = (float*)d_out;

    char* ws = (char*)d_ws;
    size_t off = 0;
    auto alloc = [&](size_t bytes) -> void* {
        void* p = ws + off;
        off += (bytes + 255) & ~(size_t)255;
        return p;
    };
    u16* tn      = (u16*)alloc((size_t)MTOT * CH * 2);
    u16* qkvw_bf = (u16*)alloc((size_t)TC * CH * 2);
    u16* outw_bf = (u16*)alloc((size_t)CH * CH * 2);
    u16* qb      = (u16*)alloc((size_t)BB * NH * SPA * DH * 2);
    u16* kb      = (u16*)alloc((size_t)BB * NH * SPA * DH * 2);
    u16* vtb     = (u16*)alloc((size_t)BB * NH * SPA * DH * 2);
    u16* ao      = (u16*)alloc((size_t)MTOT * CH * 2);

    int n4a = TC * CH / 4;
    cvtln_kernel<<<LNB + CVTB, 256, 0, stream>>>(
        qkv_w, qkvw_bf, n4a, out_w, outw_bf, x, norm_w, norm_b, tn);
    gemm_qkv<<<dim3(TC / 128, (MTOT + 127) / 128), 256, 0, stream>>>(
        tn, qkvw_bf, qb, kb, vtb);
    attn_kernel<<<1032, 256, 0, stream>>>(qb, kb, vtb, ao);
    gemm_out<<<dim3(CH / 64, (MTOT + 127) / 128), 256, 0, stream>>>(
        ao, outw_bf, x, out_b, out);
}

// Round 12
// 232.921 us; speedup vs baseline: 1.0078x; 1.0078x over previous
//
#include <hip/hip_runtime.h>

typedef unsigned short u16;
typedef unsigned int u32;

#define SPA 2744        // 14*14*14 tokens
#define CH  768
#define NH  12
#define DH  64
#define BB  2
#define TC  2304        // 3*CH
#define MTOT (BB*SPA)   // 5488
#define LNB 343         // LN blocks (16 tokens each, 343*16 = 5488 exactly)
#define CVTB 2304       // weight-cvt blocks, dispatched after LN

typedef __bf16 bf16x8_t __attribute__((ext_vector_type(8)));
typedef __bf16 bf16x4_t __attribute__((ext_vector_type(4)));
typedef short  s16x4    __attribute__((ext_vector_type(4)));
typedef float  f32x4_t  __attribute__((ext_vector_type(4)));

static __device__ __forceinline__ u16 f2bf(float f) {
    union { float f; u32 u; } v; v.f = f;
    u32 u = v.u;
    u += 0x7fffu + ((u >> 16) & 1u);   // RNE
    return (u16)(u >> 16);
}

// async global->LDS, 16B per lane. LDS dest = wave-uniform base + lane*16.
static __device__ __forceinline__ void gld16(const u16* g, u16* l) {
    __builtin_amdgcn_global_load_lds(
        (const __attribute__((address_space(1))) u32*)(size_t)g,
        (__attribute__((address_space(3))) u32*)(u32)(size_t)l, 16, 0, 0);
}

// ---------------- fused: LayerNorm (blocks < LNB, FIRST) + weight cvt ----------
__global__ __launch_bounds__(256) void cvtln_kernel(const float* __restrict__ qkv_w,
                                                    u16* __restrict__ qkvw_bf, int n4a,
                                                    const float* __restrict__ out_w,
                                                    u16* __restrict__ outw_bf,
                                                    const float* __restrict__ x,
                                                    const float* __restrict__ w,
                                                    const float* __restrict__ bta,
                                                    u16* __restrict__ tn) {
    int tid = threadIdx.x;
    if (blockIdx.x >= LNB) {
        int i = (blockIdx.x - LNB) * 256 + tid;   // covers n4a + n4b exactly
        const float* src; u16* dst; int idx;
        if (i < n4a) { src = qkv_w; dst = qkvw_bf; idx = i; }
        else { src = out_w; dst = outw_bf; idx = i - n4a; }
        float4 f = ((const float4*)src)[idx];
        uint2 o;
        o.x = (u32)f2bf(f.x) | ((u32)f2bf(f.y) << 16);
        o.y = (u32)f2bf(f.z) | ((u32)f2bf(f.w) << 16);
        ((uint2*)dst)[idx] = o;
        return;
    }
    int bid = blockIdx.x;                         // [0,343)
    __shared__ f32x4_t redS[4][4];
    __shared__ f32x4_t redQ[4][4];
    __shared__ u16 T[64][22];                     // [ch_local][token], pad 22
    int grp = tid & 3, chl = tid >> 2;            // grp: 4 token-groups, chl in [0,64)
    int wvi = tid >> 6, lane = tid & 63;
    int tok0 = bid * 16 + grp * 4;                // groups of 4 never straddle b
    int b = tok0 / SPA, n = tok0 - b * SPA;
    const float* base = x + (size_t)b * CH * SPA + n;

    f32x4_t s4 = {0.f, 0.f, 0.f, 0.f}, q4 = {0.f, 0.f, 0.f, 0.f};
    for (int c0 = 0; c0 < CH; c0 += 64) {
        float4 v = *(const float4*)(base + (size_t)(c0 + chl) * SPA);
        s4[0] += v.x; s4[1] += v.y; s4[2] += v.z; s4[3] += v.w;
        q4[0] += v.x * v.x; q4[1] += v.y * v.y; q4[2] += v.z * v.z; q4[3] += v.w * v.w;
    }
#pragma unroll
    for (int m = 4; m <= 32; m <<= 1)
#pragma unroll
        for (int e = 0; e < 4; e++) {
            s4[e] += __shfl_xor(s4[e], m);
            q4[e] += __shfl_xor(q4[e], m);
        }
    if (lane < 4) { redS[wvi][lane] = s4; redQ[wvi][lane] = q4; }
    __syncthreads();
    f32x4_t st = redS[0][grp], qt = redQ[0][grp];
#pragma unroll
    for (int wv2 = 1; wv2 < 4; wv2++) {
        f32x4_t a = redS[wv2][grp], c = redQ[wv2][grp];
#pragma unroll
        for (int e = 0; e < 4; e++) { st[e] += a[e]; qt[e] += c[e]; }
    }
    f32x4_t mean4, rstd4;
#pragma unroll
    for (int e = 0; e < 4; e++) {
        mean4[e] = st[e] * (1.0f / CH);
        rstd4[e] = rsqrtf(qt[e] * (1.0f / CH) - mean4[e] * mean4[e] + 1e-5f);
    }

    int tokl = tid >> 4, qq = tid & 15;           // tokl in [0,16), qq in [0,16)
    int g2 = bid * 16 + tokl;                     // always < MTOT (343*16 = 5488)
    for (int c0 = 0; c0 < CH; c0 += 64) {
        __syncthreads();
        {
            int cc = c0 + chl;
            float4 v = *(const float4*)(base + (size_t)cc * SPA);
            float ws = w[cc], bs = bta[cc];
            union { u16 h4[4]; uint2 u; } pk;
            pk.h4[0] = f2bf((v.x - mean4[0]) * rstd4[0] * ws + bs);
            pk.h4[1] = f2bf((v.y - mean4[1]) * rstd4[1] * ws + bs);
            pk.h4[2] = f2bf((v.z - mean4[2]) * rstd4[2] * ws + bs);
            pk.h4[3] = f2bf((v.w - mean4[3]) * rstd4[3] * ws + bs);
            *(uint2*)(&T[chl][grp * 4]) = pk.u;
        }
        __syncthreads();
        union { u16 h[4]; uint2 u; } pk;
#pragma unroll
        for (int e = 0; e < 4; e++) pk.h[e] = T[qq * 4 + e][tokl];
        *(uint2*)(tn + (size_t)g2 * CH + c0 + qq * 4) = pk.u;
    }
}

// ---------------- QKV GEMM: C[m][n] = tn[m][k]*W[n][k], scatter epilogue ----------
// bounds (256,4): LDS 16KB -> 4 blocks/CU, grid 774 <= 1024 slots (no tail).
__global__ __launch_bounds__(256, 4) void gemm_qkv(const u16* __restrict__ A,
                                                   const u16* __restrict__ Bw,
                                                   u16* __restrict__ out0,
                                                   u16* __restrict__ out1,
                                                   u16* __restrict__ out2) {
    const int M = MTOT, K = CH;
    __shared__ __align__(16) u16 As[128 * 32];
    __shared__ __align__(16) u16 Bs[128 * 32];
    int tid = threadIdx.x;
    int m0 = blockIdx.y * 128;
    int n0 = blockIdx.x * 128;
    int wv = tid >> 6, lane = tid & 63;
    int wm = (wv >> 1) * 64, wn = (wv & 1) * 64;
    int quad = lane >> 4, l16 = lane & 15;

    f32x4_t zero = {0.f, 0.f, 0.f, 0.f};
    f32x4_t acc[4][4];
#pragma unroll
    for (int i = 0; i < 4; i++)
#pragma unroll
        for (int j = 0; j < 4; j++) acc[i][j] = zero;

    int rl = lane >> 2, pos = lane & 3;
    int sw = (l16 >> 1) & 3;
    for (int k0 = 0; k0 < K; k0 += 32) {
        __syncthreads();
#pragma unroll
        for (int p = 0; p < 2; p++) {
            int rbase = p * 64 + wv * 16;
            int row = rbase + rl;
            int gch = pos ^ ((row >> 1) & 3);
            int gm = m0 + row; if (gm >= M) gm = M - 1;
            gld16(A + (size_t)gm * K + k0 + gch * 8, As + rbase * 32);
            gld16(Bw + (size_t)(n0 + row) * K + k0 + gch * 8, Bs + rbase * 32);
        }
        __syncthreads();
        bf16x8_t af[4], bfr[4];
#pragma unroll
        for (int i = 0; i < 4; i++)
            af[i] = *(const bf16x8_t*)(As + (wm + i * 16 + l16) * 32 + ((quad ^ sw) * 8));
#pragma unroll
        for (int j = 0; j < 4; j++)
            bfr[j] = *(const bf16x8_t*)(Bs + (wn + j * 16 + l16) * 32 + ((quad ^ sw) * 8));
#pragma unroll
        for (int i = 0; i < 4; i++)
#pragma unroll
            for (int j = 0; j < 4; j++)
                acc[i][j] = __builtin_amdgcn_mfma_f32_16x16x32_bf16(af[i], bfr[j], acc[i][j], 0, 0, 0);
    }

    int which = n0 / CH;                  // block-uniform (CH % 128 == 0)
    int rb = n0 - which * CH;
    u16* base = (which == 0) ? out0 : ((which == 1) ? out1 : out2);
    float qs = (which == 0) ? 0.18033688011112042f : 1.0f;  // dh^-0.5*log2(e)
#pragma unroll
    for (int i = 0; i < 4; i++)
#pragma unroll
        for (int r = 0; r < 4; r++) {
            int gm = m0 + wm + i * 16 + quad * 4 + r;
            if (gm < M) {
                int b = gm / SPA, n = gm - b * SPA;
#pragma unroll
                for (int j = 0; j < 4; j++) {
                    int rem = rb + wn + j * 16 + l16;
                    int h = rem >> 6, d = rem & 63;
                    base[((size_t)(b * NH + h) * SPA + n) * DH + d] = f2bf(acc[i][j][r] * qs);
                }
            }
        }
}

// ---------------- out-proj GEMM, 128x64 tiles, fused bias+residual epilogue ----
__global__ __launch_bounds__(256, 4) void gemm_out(const u16* __restrict__ A,
                                                   const u16* __restrict__ Bw,
                                                   const float* __restrict__ xres,
                                                   const float* __restrict__ ob,
                                                   float* __restrict__ fout) {
    const int M = MTOT, K = CH;
    __shared__ __align__(16) u16 As[128 * 32];
    __shared__ __align__(16) u16 Bs[64 * 32];
    int tid = threadIdx.x;
    int m0 = blockIdx.y * 128;
    int n0 = blockIdx.x * 64;
    int wv = tid >> 6, lane = tid & 63;
    int wm = (wv >> 1) * 64, wn = (wv & 1) * 32;
    int quad = lane >> 4, l16 = lane & 15;

    f32x4_t zero = {0.f, 0.f, 0.f, 0.f};
    f32x4_t acc[4][2];
#pragma unroll
    for (int i = 0; i < 4; i++)
#pragma unroll
        for (int j = 0; j < 2; j++) acc[i][j] = zero;

    int rl = lane >> 2, pos = lane & 3;
    int sw = (l16 >> 1) & 3;
    for (int k0 = 0; k0 < K; k0 += 32) {
        __syncthreads();
#pragma unroll
        for (int p = 0; p < 2; p++) {
            int rbase = p * 64 + wv * 16;
            int row = rbase + rl;
            int gch = pos ^ ((row >> 1) & 3);
            int gm = m0 + row; if (gm >= M) gm = M - 1;
            gld16(A + (size_t)gm * K + k0 + gch * 8, As + rbase * 32);
        }
        {
            int row = wv * 16 + rl;
            int gch = pos ^ ((row >> 1) & 3);
            gld16(Bw + (size_t)(n0 + row) * K + k0 + gch * 8, Bs + (wv * 16) * 32);
        }
        __syncthreads();
        bf16x8_t af[4], bfr[2];
#pragma unroll
        for (int i = 0; i < 4; i++)
            af[i] = *(const bf16x8_t*)(As + (wm + i * 16 + l16) * 32 + ((quad ^ sw) * 8));
#pragma unroll
        for (int j = 0; j < 2; j++)
            bfr[j] = *(const bf16x8_t*)(Bs + (wn + j * 16 + l16) * 32 + ((quad ^ sw) * 8));
#pragma unroll
        for (int i = 0; i < 4; i++)
#pragma unroll
            for (int j = 0; j < 2; j++)
                acc[i][j] = __builtin_amdgcn_mfma_f32_16x16x32_bf16(af[i], bfr[j], acc[i][j], 0, 0, 0);
    }

    // fused: lane holds 4 consecutive tokens (quad*4+r) for channel gn
#pragma unroll
    for (int i = 0; i < 4; i++) {
        int gm0 = m0 + wm + i * 16 + quad * 4;
        if (gm0 < M) {                    // groups of 4, M%4==0, SPA%4==0
            int b = gm0 / SPA;
            int n = gm0 - b * SPA;
#pragma unroll
            for (int j = 0; j < 2; j++) {
                int gn = n0 + wn + j * 16 + l16;
                size_t xo = ((size_t)(b * CH + gn)) * SPA + n;
                float4 xv = *(const float4*)(xres + xo);
                float bias = ob[gn];
                float4 rr;
                rr.x = xv.x + bias + acc[i][j][0];
                rr.y = xv.y + bias + acc[i][j][1];
                rr.z = xv.z + bias + acc[i][j][2];
                rr.w = xv.w + bias + acc[i][j][3];
                *(float4*)(fout + xo) = rr;
            }
        }
    }
}

// ---------------- V transpose: [bh][n][d] -> [bh][d][n] ----------------
__global__ __launch_bounds__(256) void vtrans_kernel(const u16* __restrict__ v,
                                                     u16* __restrict__ vt) {
    __shared__ __align__(16) u16 T[64 * 72];
    int bh = blockIdx.y;
    int n0 = blockIdx.x * 64;
    int tid = threadIdx.x;
#pragma unroll
    for (int h = 0; h < 2; h++) {
        int chunk = tid + h * 256;
        int r = chunk >> 3, cs = chunk & 7;
        int n = n0 + r;
        int4 val = make_int4(0, 0, 0, 0);
        if (n < SPA) val = *(const int4*)(v + ((size_t)bh * SPA + n) * DH + cs * 8);
        *(int4*)(T + r * 72 + cs * 8) = val;
    }
    __syncthreads();
#pragma unroll
    for (int h = 0; h < 2; h++) {
        int chunk = tid + h * 256;
        int d = chunk >> 3, cs = chunk & 7;
        int nb = n0 + cs * 8;
        if (nb < SPA) {
            union { u16 s[8]; int4 v4; } tmp;
#pragma unroll
            for (int e = 0; e < 8; e++) tmp.s[e] = T[(cs * 8 + e) * 72 + d];
            *(int4*)(vt + ((size_t)bh * DH + d) * SPA + nb) = tmp.v4;
        }
    }
}

// ---------------- flash attention v18: 64-kv tiles, 4 blocks/CU ----------------
// v17 structure (q64 tiles, wave-level kv-split, K gld16+swizzle, padded V,
// _1k PV, MFMA lacc, LDS combine) with kv super-tile 96 -> 64:
// LDS 51 -> 35 KB -> FOUR blocks/CU (1032 blocks vs 1024 slots ~ single
// resident round; v17's 4.03-avg/3-cap imbalance eliminated). 43 si vs 29.
// Same mechanism as v16's win (kv 128->96, 2->3 blocks/CU, +6us).
__global__ __launch_bounds__(256, 4) void attn_kernel(const u16* __restrict__ q,
                                                      const u16* __restrict__ k,
                                                      const u16* __restrict__ vt,
                                                      u16* __restrict__ out) {
    __shared__ __align__(16) u16 Kbuf[2][64 * 64];    // [kv_local][d] swizzled
    __shared__ __align__(16) u16 Vbuf[2][64 * 76];    // [d][kv_local] padded (+12)
    int g = blockIdx.x;                 // 1032 = 8 xcd * (3 bh * 43 qtiles)
    int xcd = g & 7, slot = g >> 3;     // slot in [0,129)
    int bh = xcd * 3 + slot % 3;
    int qg = slot / 3;                  // [0,43)
    int b = bh / NH, h = bh - b * NH;
    int tid = threadIdx.x;
    int wv = tid >> 6, lane = tid & 63;
    int quad = lane >> 4, l16 = lane & 15;
    int qhalf = wv & 1, khalf = wv >> 1;
    int koff = khalf * 32;              // this wave's kv-local window base
    int q0w = qg * 64 + qhalf * 32;

    const u16* qgp = q + (size_t)bh * SPA * DH;
    const u16* kg = k + (size_t)bh * SPA * DH;
    const u16* vg = vt + (size_t)bh * DH * SPA;

    bf16x8_t bq[2][2];
    int qglob[2];
#pragma unroll
    for (int qf = 0; qf < 2; qf++) {
        int qq = q0w + qf * 16 + l16;
        qglob[qf] = qq;
        int qld = (qq < SPA) ? qq : (SPA - 1);
#pragma unroll
        for (int ks = 0; ks < 2; ks++)
            bq[qf][ks] = *(const bf16x8_t*)(qgp + (size_t)qld * DH + ks * 32 + quad * 8);
    }

    f32x4_t zero = {0.f, 0.f, 0.f, 0.f};
    f32x4_t o[2][4];
#pragma unroll
    for (int qf = 0; qf < 2; qf++)
#pragma unroll
        for (int i = 0; i < 4; i++) o[qf][i] = zero;
    f32x4_t lacc[2];
    lacc[0] = zero; lacc[1] = zero;
    s16x4 ones;
    ones[0] = ones[1] = ones[2] = ones[3] = (short)0x3F80;  // bf16 1.0 x4

    int rl8 = lane >> 3, pos8 = lane & 7;
    int sw8 = l16 & 7;
    int vd = tid >> 2, vc = (tid & 3) * 16;   // 16 kv per thread (64/4)

    // ---- prologue: stage super-tile 0 (64 kv, all waves) ----
#pragma unroll
    for (int p = 0; p < 2; p++) {
        int rbase = p * 32 + wv * 8;
        int row = rbase + rl8;
        int gch = pos8 ^ (row & 7);
        gld16(kg + (size_t)row * DH + gch * 8, Kbuf[0] + rbase * 64);
    }
#pragma unroll
    for (int s2 = 0; s2 < 2; s2++)
        *(int4*)(Vbuf[0] + vd * 76 + vc + s2 * 8) =
            *(const int4*)(vg + (size_t)vd * SPA + vc + s2 * 8);

    for (int si = 0; si < 43; si++) {           // 43*64 = 2752 >= 2744
        __syncthreads();
        int cur = si & 1, nxt = cur ^ 1;
        int kv0 = si * 64;
        bool hn = (si < 42);
        int4 vp0, vp1;
        if (hn) {
            int kb = kv0 + 64;
#pragma unroll
            for (int p = 0; p < 2; p++) {
                int rbase = p * 32 + wv * 8;
                int row = rbase + rl8;
                int gch = pos8 ^ (row & 7);
                int kr = kb + row; if (kr >= SPA) kr = SPA - 1;
                gld16(kg + (size_t)kr * DH + gch * 8, Kbuf[nxt] + rbase * 64);
            }
            int c0 = kb + vc;
            int a0 = c0;      if (a0 > SPA - 8) a0 = SPA - 8;
            int a1 = c0 + 8;  if (a1 > SPA - 8) a1 = SPA - 8;
            vp0 = *(const int4*)(vg + (size_t)vd * SPA + a0);
            vp1 = *(const int4*)(vg + (size_t)vd * SPA + a1);
        }

        // ---- QK + exp over this wave's 32-kv window ----
        s16x4 bp[2][2];
#pragma unroll
        for (int i = 0; i < 2; i++) {
            const u16* krow = Kbuf[cur] + (koff + i * 16 + l16) * 64;
            bf16x8_t ak0 = *(const bf16x8_t*)(krow + ((quad ^ sw8) * 8));
            bf16x8_t ak1 = *(const bf16x8_t*)(krow + (((4 + quad) ^ sw8) * 8));
            f32x4_t s0 = __builtin_amdgcn_mfma_f32_16x16x32_bf16(ak0, bq[0][0], zero, 0, 0, 0);
            s0 = __builtin_amdgcn_mfma_f32_16x16x32_bf16(ak1, bq[0][1], s0, 0, 0, 0);
            f32x4_t s1 = __builtin_amdgcn_mfma_f32_16x16x32_bf16(ak0, bq[1][0], zero, 0, 0, 0);
            s1 = __builtin_amdgcn_mfma_f32_16x16x32_bf16(ak1, bq[1][1], s1, 0, 0, 0);
            bf16x4_t p0, p1;
            if (si != 42) {
#pragma unroll
                for (int r = 0; r < 4; r++) {
                    p0[r] = (__bf16)__builtin_amdgcn_exp2f(s0[r]);
                    p1[r] = (__bf16)__builtin_amdgcn_exp2f(s1[r]);
                }
            } else {
#pragma unroll
                for (int r = 0; r < 4; r++) {
                    float e0 = __builtin_amdgcn_exp2f(s0[r]);
                    float e1 = __builtin_amdgcn_exp2f(s1[r]);
                    bool bad = (kv0 + koff + i * 16 + quad * 4 + r) >= SPA;
                    p0[r] = (__bf16)(bad ? 0.f : e0);
                    p1[r] = (__bf16)(bad ? 0.f : e1);
                }
            }
            union { bf16x4_t b; s16x4 s; } u0, u1;
            u0.b = p0; u1.b = p1;
            bp[0][i] = u0.s; bp[1][i] = u1.s;
        }

        // park next V tile (loads are QK-phase old by now)
        if (hn) {
            *(int4*)(Vbuf[nxt] + vd * 76 + vc)     = vp0;
            *(int4*)(Vbuf[nxt] + vd * 76 + vc + 8) = vp1;
        }

        // ---- l += ones·P ; O^T += V^T·P (this wave's kv window) ----
#pragma unroll
        for (int c = 0; c < 2; c++) {
            lacc[0] = __builtin_amdgcn_mfma_f32_16x16x16bf16_1k(ones, bp[0][c], lacc[0], 0, 0, 0);
            lacc[1] = __builtin_amdgcn_mfma_f32_16x16x16bf16_1k(ones, bp[1][c], lacc[1], 0, 0, 0);
#pragma unroll
            for (int i = 0; i < 4; i++) {
                s16x4 av = *(const s16x4*)(Vbuf[cur] + (i * 16 + l16) * 76 + koff + c * 16 + quad * 4);
                o[0][i] = __builtin_amdgcn_mfma_f32_16x16x16bf16_1k(av, bp[0][c], o[0][i], 0, 0, 0);
                o[1][i] = __builtin_amdgcn_mfma_f32_16x16x16bf16_1k(av, bp[1][c], o[1][i], 0, 0, 0);
            }
        }
    }

    // ---- combine kv-halves through LDS (reuse Vbuf; 128 lanes x 36 f32) ----
    __syncthreads();
    float* lsh = (float*)Vbuf;                    // 19456 B >= 18432 B needed
    if (wv >= 2) {
        int base = ((wv - 2) * 64 + lane) * 36;
#pragma unroll
        for (int qf = 0; qf < 2; qf++)
#pragma unroll
            for (int i = 0; i < 4; i++)
                *(f32x4_t*)(lsh + base + qf * 16 + i * 4) = o[qf][i];
        lsh[base + 32] = lacc[0][0];
        lsh[base + 33] = lacc[1][0];
    }
    __syncthreads();
    if (wv < 2) {
        int base = (wv * 64 + lane) * 36;
#pragma unroll
        for (int qf = 0; qf < 2; qf++)
#pragma unroll
            for (int i = 0; i < 4; i++) {
                f32x4_t t = *(const f32x4_t*)(lsh + base + qf * 16 + i * 4);
#pragma unroll
                for (int r = 0; r < 4; r++) o[qf][i][r] += t[r];
            }
        float lsum[2];
        lsum[0] = lacc[0][0] + lsh[base + 32];
        lsum[1] = lacc[1][0] + lsh[base + 33];
#pragma unroll
        for (int qf = 0; qf < 2; qf++) {
            int qq = qglob[qf];
            if (qq < SPA) {
                float inv = 1.0f / lsum[qf];
                u16* op = out + ((size_t)(b * SPA + qq)) * CH + h * DH;
#pragma unroll
                for (int i = 0; i < 4; i++) {
                    bf16x4_t ov;
#pragma unroll
                    for (int r = 0; r < 4; r++) ov[r] = (__bf16)(o[qf][i][r] * inv);
                    *(bf16x4_t*)(op + i * 16 + quad * 4) = ov;
                }
            }
        }
    }
}

extern "C" void kernel_launch(void* const* d_in, const int* in_sizes, int n_in,
                              void* d_out, int out_size, void* d_ws, size_t ws_size,
                              hipStream_t stream) {
    const float* x      = (const float*)d_in[0];
    const float* norm_w = (const float*)d_in[1];
    const float* norm_b = (const float*)d_in[2];
    const float* qkv_w  = (const float*)d_in[3];
    const float* out_w  = (const float*)d_in[4];
    const float* out_b  = (const float*)d_in[5];
    float* out = (float*)d_out;

    char* ws = (char*)d_ws;
    size_t off = 0;
    auto alloc = [&](size_t bytes) -> void* {
        void* p = ws + off;
        off += (bytes + 255) & ~(size_t)255;
        return p;
    };
    u16* tn      = (u16*)alloc((size_t)MTOT * CH * 2);
    u16* qkvw_bf = (u16*)alloc((size_t)TC * CH * 2);
    u16* outw_bf = (u16*)alloc((size_t)CH * CH * 2);
    u16* qb      = (u16*)alloc((size_t)BB * NH * SPA * DH * 2);
    u16* kb      = (u16*)alloc((size_t)BB * NH * SPA * DH * 2);
    u16* vb      = (u16*)alloc((size_t)BB * NH * SPA * DH * 2);
    u16* vtb     = (u16*)alloc((size_t)BB * NH * SPA * DH * 2);
    u16* ao      = (u16*)alloc((size_t)MTOT * CH * 2);

    int n4a = TC * CH / 4;
    cvtln_kernel<<<LNB + CVTB, 256, 0, stream>>>(
        qkv_w, qkvw_bf, n4a, out_w, outw_bf, x, norm_w, norm_b, tn);
    gemm_qkv<<<dim3(TC / 128, (MTOT + 127) / 128), 256, 0, stream>>>(
        tn, qkvw_bf, qb, kb, vb);
    vtrans_kernel<<<dim3((SPA + 63) / 64, BB * NH), 256, 0, stream>>>(vb, vtb);
    attn_kernel<<<1032, 256, 0, stream>>>(qb, kb, vtb, ao);
    gemm_out<<<dim3(CH / 64, (MTOT + 127) / 128), 256, 0, stream>>>(
        ao, outw_bf, x, out_b, out);
}